// Round 2
// baseline (490.968 us; speedup 1.0000x reference)
//
#include <hip/hip_runtime.h>

#define BB 64
#define CC 1024
#define QQ 128
#define HH 512

typedef short bf16x8 __attribute__((ext_vector_type(8)));
typedef float f32x4 __attribute__((ext_vector_type(4)));

#define GLD16(g, l)                                                            \
    __builtin_amdgcn_global_load_lds(                                          \
        (const __attribute__((address_space(1))) unsigned int*)(g),            \
        (__attribute__((address_space(3))) unsigned int*)(l), 16, 0, 0)

__device__ __forceinline__ unsigned short f2bf(float f) {
    unsigned u = __float_as_uint(f);
    u += 0x7FFF + ((u >> 16) & 1);          // RNE
    return (unsigned short)(u >> 16);
}
__device__ __forceinline__ unsigned pk2(float lo, float hi) {
    return (unsigned)f2bf(lo) | ((unsigned)f2bf(hi) << 16);
}

// ---------------- K0: sub0[b,q] = dot(xq[b,q,:], W0); also zero colsum ----
__global__ __launch_bounds__(256) void k_sub0(const float* __restrict__ xq,
                                              const float* __restrict__ w0,
                                              float* __restrict__ sub0,
                                              float* __restrict__ colsum) {
    if (blockIdx.x < 32) colsum[blockIdx.x * 256 + threadIdx.x] = 0.0f;
    int wave = threadIdx.x >> 6;
    int lane = threadIdx.x & 63;
    int row  = blockIdx.x * 4 + wave;
    const float* p = xq + (size_t)row * HH + lane * 8;
    float4 a0 = *(const float4*)(p);
    float4 a1 = *(const float4*)(p + 4);
    float4 b0 = *(const float4*)(w0 + lane * 8);
    float4 b1 = *(const float4*)(w0 + lane * 8 + 4);
    float s = a0.x*b0.x + a0.y*b0.y + a0.z*b0.z + a0.w*b0.w
            + a1.x*b1.x + a1.y*b1.y + a1.z*b1.z + a1.w*b1.w;
    #pragma unroll
    for (int off = 32; off; off >>= 1) s += __shfl_xor(s, off);
    if (lane == 0) sub0[row] = s;
}

// ---------------- K_prep: xqw2b[q][h]=bf16(xq*w2); xqmT[h][q]=bf16(xq*qm) --
__global__ __launch_bounds__(256) void k_prep(const float* __restrict__ xq,
                                              const float* __restrict__ w2,
                                              const float* __restrict__ qmask,
                                              unsigned short* __restrict__ xqw2b,
                                              unsigned short* __restrict__ xqmT) {
    int b  = blockIdx.y;
    int ht = blockIdx.x * 128;
    int tid = threadIdx.x;
    __shared__ __align__(16) unsigned short sT[128][132];   // [q][h-local], pad

    {
        int q  = tid >> 1;
        int hh = (tid & 1) * 64;
        float qm = qmask[b * QQ + q];
        const float* xp = xq + ((size_t)b * QQ + q) * HH + ht + hh;
        unsigned short* wr = xqw2b + ((size_t)b * QQ + q) * HH + ht + hh;
        #pragma unroll
        for (int i = 0; i < 16; i++) {
            float4 v = *(const float4*)(xp + i * 4);
            float4 w = *(const float4*)(w2 + ht + hh + i * 4);
            uint2 pw; pw.x = pk2(v.x * w.x, v.y * w.y);
                      pw.y = pk2(v.z * w.z, v.w * w.w);
            *(uint2*)(wr + i * 4) = pw;
            uint2 pm; pm.x = pk2(v.x * qm, v.y * qm);
                      pm.y = pk2(v.z * qm, v.w * qm);
            *(uint2*)(&sT[q][hh + i * 4]) = pm;
        }
    }
    __syncthreads();
    {
        int h  = tid >> 1;
        int qh = (tid & 1) * 64;
        unsigned short* orow = xqmT + ((size_t)b * HH + ht + h) * QQ + qh;
        #pragma unroll
        for (int i = 0; i < 8; i++) {
            uint4 o;
            o.x = (unsigned)sT[qh + i*8 + 0][h] | ((unsigned)sT[qh + i*8 + 1][h] << 16);
            o.y = (unsigned)sT[qh + i*8 + 2][h] | ((unsigned)sT[qh + i*8 + 3][h] << 16);
            o.z = (unsigned)sT[qh + i*8 + 4][h] | ((unsigned)sT[qh + i*8 + 5][h] << 16);
            o.w = (unsigned)sT[qh + i*8 + 6][h] | ((unsigned)sT[qh + i*8 + 7][h] << 16);
            *(uint4*)(orow + i * 8) = o;
        }
    }
}

// ---------------- K1: S = xc · xqw2^T (MFMA) -> E=exp(S), rowsum, colsum ---
// c-tile 64 (4 blocks/CU), 2-phase double-buffered
__global__ __launch_bounds__(256) void k_scores(
    const float* __restrict__ xc, const unsigned short* __restrict__ xqw2b,
    const float* __restrict__ w1, const float* __restrict__ cmask,
    const float* __restrict__ qmask, const float* __restrict__ bias,
    const float* __restrict__ sub0, unsigned short* __restrict__ Ebf,
    float* __restrict__ rowsum, float* __restrict__ colsum) {
    int b  = blockIdx.y;
    int c0 = blockIdx.x * 64;
    int tid  = threadIdx.x;
    int lane = tid & 63, wave = tid >> 6;
    int quad = lane >> 4, lcol = lane & 15;
    int wrow = (wave >> 1) * 32, wcol = (wave & 1) * 64;

    __shared__ __align__(16) unsigned short sA[2][64][32];   // [c][k] bf16
    __shared__ __align__(16) unsigned short sB[2][128][32];  // [q][k] bf16
    __shared__ float sW1[512];
    __shared__ float sSub1[64];
    __shared__ float sS0[128], sQm[128], sCm[64];
    __shared__ float sRowP[2][64], sColP[2][128];

    sW1[tid] = w1[tid]; sW1[tid + 256] = w1[tid + 256];
    if (tid < 128) {
        sS0[tid] = sub0[b * QQ + tid] + bias[0];
        sQm[tid] = qmask[b * QQ + tid];
    }
    if (tid < 64) sCm[tid] = cmask[b * CC + c0 + tid];

    f32x4 acc[2][4];
    #pragma unroll
    for (int i = 0; i < 2; i++)
        #pragma unroll
        for (int j = 0; j < 4; j++) acc[i][j] = (f32x4)0.0f;
    float s1 = 0.0f;

    int arow = tid >> 2, akh = (tid & 3) * 8;
    const float* gbase = xc + ((size_t)(b * CC + c0 + arow)) * HH + akh;

    __syncthreads();   // sW1 ready

    // ---- prologue: stage chunk 0 into buf 0 ----
    {
        float4 v0 = *(const float4*)(gbase);
        float4 v1 = *(const float4*)(gbase + 4);
        const float* wp = sW1 + akh;
        s1 += v0.x*wp[0] + v0.y*wp[1] + v0.z*wp[2] + v0.w*wp[3]
            + v1.x*wp[4] + v1.y*wp[5] + v1.z*wp[6] + v1.w*wp[7];
        uint4 p;
        p.x = pk2(v0.x, v0.y); p.y = pk2(v0.z, v0.w);
        p.z = pk2(v1.x, v1.y); p.w = pk2(v1.z, v1.w);
        *(uint4*)&sA[0][arow][akh] = p;
    }
    #pragma unroll
    for (int j = 0; j < 2; j++) {
        int chunk = wave * 2 + j;
        int row = chunk * 16 + (lane >> 2);
        GLD16(xqw2b + ((size_t)b * QQ + row) * HH + (lane & 3) * 8,
              (unsigned short*)sB[0] + chunk * 512);
    }
    __syncthreads();

    for (int t = 0; t < 16; ++t) {
        int cur = t & 1, alt = cur ^ 1;
        bool pf = (t < 15);
        int kn = (t + 1) * 32;
        float4 v0, v1;
        // --- issue next-chunk loads early (hide under MFMA) ---
        if (pf) {
            const float* gp = gbase + kn;
            v0 = *(const float4*)(gp);
            v1 = *(const float4*)(gp + 4);
            #pragma unroll
            for (int j = 0; j < 2; j++) {
                int chunk = wave * 2 + j;
                int row = chunk * 16 + (lane >> 2);
                GLD16(xqw2b + ((size_t)b * QQ + row) * HH + kn + (lane & 3) * 8,
                      (unsigned short*)sB[alt] + chunk * 512);
            }
        }
        // --- MFMA on current buffers ---
        bf16x8 af[2];
        #pragma unroll
        for (int mi = 0; mi < 2; mi++)
            af[mi] = *(const bf16x8*)&sA[cur][wrow + mi * 16 + lcol][quad * 8];
        #pragma unroll
        for (int ni = 0; ni < 4; ni++) {
            bf16x8 bfr = *(const bf16x8*)&sB[cur][wcol + ni * 16 + lcol][quad * 8];
            #pragma unroll
            for (int mi = 0; mi < 2; mi++)
                acc[mi][ni] = __builtin_amdgcn_mfma_f32_16x16x32_bf16(
                    af[mi], bfr, acc[mi][ni], 0, 0, 0);
        }
        // --- convert + LDS-write next chunk (waits on loads AFTER MFMA) ---
        if (pf) {
            const float* wp = sW1 + kn + akh;
            s1 += v0.x*wp[0] + v0.y*wp[1] + v0.z*wp[2] + v0.w*wp[3]
                + v1.x*wp[4] + v1.y*wp[5] + v1.z*wp[6] + v1.w*wp[7];
            uint4 p;
            p.x = pk2(v0.x, v0.y); p.y = pk2(v0.z, v0.w);
            p.z = pk2(v1.x, v1.y); p.w = pk2(v1.z, v1.w);
            *(uint4*)&sA[alt][arow][akh] = p;
        }
        __syncthreads();   // implicit vmcnt(0): next GLD16s complete here
    }

    // sub1 finalize (4 k-groups per row)
    s1 += __shfl_xor(s1, 1);
    s1 += __shfl_xor(s1, 2);
    if ((tid & 3) == 0) sSub1[arow] = s1;
    __syncthreads();

    // epilogue: E = exp(S), rowsum/colsum partials
    float rsp[2][4];
    float csp[4] = {0.f, 0.f, 0.f, 0.f};
    #pragma unroll
    for (int mi = 0; mi < 2; mi++)
        #pragma unroll
        for (int r = 0; r < 4; r++) rsp[mi][r] = 0.f;

    #pragma unroll
    for (int mi = 0; mi < 2; mi++) {
        #pragma unroll
        for (int ni = 0; ni < 4; ni++) {
            int col = wcol + ni * 16 + lcol;
            float qm = sQm[col], s0 = sS0[col];
            #pragma unroll
            for (int r = 0; r < 4; r++) {
                int row = wrow + mi * 16 + quad * 4 + r;
                float e = __expf(acc[mi][ni][r] + sSub1[row] + s0);
                acc[mi][ni][r] = e;
                rsp[mi][r] += e * qm;
                csp[ni] += e * sCm[row];
            }
        }
    }
    #pragma unroll
    for (int mi = 0; mi < 2; mi++)
        #pragma unroll
        for (int r = 0; r < 4; r++) {
            float v = rsp[mi][r];
            v += __shfl_xor(v, 1); v += __shfl_xor(v, 2);
            v += __shfl_xor(v, 4); v += __shfl_xor(v, 8);
            if (lcol == 0) sRowP[wave & 1][wrow + mi * 16 + quad * 4 + r] = v;
        }
    #pragma unroll
    for (int ni = 0; ni < 4; ni++) {
        float v = csp[ni];
        v += __shfl_xor(v, 16); v += __shfl_xor(v, 32);
        if (quad == 0) sColP[wave >> 1][wcol + ni * 16 + lcol] = v;
    }
    // E store (bf16 scalar)
    #pragma unroll
    for (int mi = 0; mi < 2; mi++)
        #pragma unroll
        for (int ni = 0; ni < 4; ni++) {
            int col = wcol + ni * 16 + lcol;
            #pragma unroll
            for (int r = 0; r < 4; r++) {
                int row = wrow + mi * 16 + quad * 4 + r;
                Ebf[((size_t)(b * CC + c0 + row)) * QQ + col] = f2bf(acc[mi][ni][r]);
            }
        }
    __syncthreads();
    if (tid < 64)
        rowsum[(size_t)b * CC + c0 + tid] = sRowP[0][tid] + sRowP[1][tid];
    if (tid < 128)
        atomicAdd(&colsum[b * QQ + tid], sColP[0][tid] + sColP[1][tid]);
}

// ---------------- K2: tmpT[h][q] = qm[q]/colsum[q] * sum_c E[c][q]*mc*xc[c][h]
// q-tile 64 (4 blocks/CU), 2-phase double-buffered
__global__ __launch_bounds__(256) void k_tmp(
    const unsigned short* __restrict__ Ebf, const float* __restrict__ xc,
    const float* __restrict__ cmask, const float* __restrict__ qmask,
    const float* __restrict__ colsum, unsigned short* __restrict__ tmpT) {
    int b  = blockIdx.y;
    int h0 = (blockIdx.x >> 1) * 64;
    int q0 = (blockIdx.x & 1) * 64;
    int tid  = threadIdx.x;
    int lane = tid & 63, wave = tid >> 6;
    int quad = lane >> 4, lcol = lane & 15;
    int wrow = (wave >> 1) * 32;      // q (local)
    int wcol = (wave & 1) * 32;       // h (local)

    __shared__ __align__(16) unsigned int sAu[2][64 * 16];  // [q][c-chunk] swizzled
    __shared__ __align__(16) unsigned int sBu[2][64 * 16];  // [h][c-chunk] swizzled
    __shared__ float sInv[64];
    if (tid < 64) sInv[tid] = qmask[b * QQ + q0 + tid] / colsum[b * QQ + q0 + tid];

    f32x4 acc[2][2];
    #pragma unroll
    for (int i = 0; i < 2; i++) { acc[i][0] = (f32x4)0.f; acc[i][1] = (f32x4)0.f; }

    int tp = tid >> 4;     // c-pair 0..15
    int tq = tid & 15;     // q-4group / h-4group

    const unsigned short* ebase = Ebf + ((size_t)b * CC + 2 * tp) * QQ + q0 + tq * 4;
    const float*          xbase = xc  + ((size_t)b * CC + 2 * tp) * HH + h0 + tq * 4;
    const float*          mbase = cmask + (size_t)b * CC + 2 * tp;

    // ---- prologue: stage c-chunk 0 into buf 0 ----
    {
        union { uint2 v; unsigned short s[4]; } r0, r1;
        r0.v = *(const uint2*)(ebase);
        r1.v = *(const uint2*)(ebase + QQ);
        float cm0 = mbase[0];
        float cm1 = mbase[1];
        float4 f0 = *(const float4*)(xbase);
        float4 f1 = *(const float4*)(xbase + HH);
        #pragma unroll
        for (int j = 0; j < 4; j++) {
            int q = tq * 4 + j;
            unsigned pk = (unsigned)r0.s[j] | ((unsigned)r1.s[j] << 16);
            sAu[0][q * 16 + (((tp >> 2) ^ (q >> 3 & 3)) << 2) + (tp & 3)] = pk;
        }
        float a0[4] = {f0.x, f0.y, f0.z, f0.w};
        float a1[4] = {f1.x, f1.y, f1.z, f1.w};
        #pragma unroll
        for (int j = 0; j < 4; j++) {
            int h = tq * 4 + j;
            unsigned pk = pk2(a0[j] * cm0, a1[j] * cm1);
            sBu[0][h * 16 + (((tp >> 2) ^ (h >> 3 & 3)) << 2) + (tp & 3)] = pk;
        }
    }
    __syncthreads();

    for (int t = 0; t < 32; ++t) {
        int cur = t & 1, alt = cur ^ 1;
        bool pf = (t < 31);
        int cn = (t + 1) * 32;
        union { uint2 v; unsigned short s[4]; } r0, r1;
        float4 f0, f1;
        float cm0, cm1;
        // --- issue next-chunk loads early ---
        if (pf) {
            r0.v = *(const uint2*)(ebase + (size_t)cn * QQ);
            r1.v = *(const uint2*)(ebase + (size_t)cn * QQ + QQ);
            cm0 = mbase[cn];
            cm1 = mbase[cn + 1];
            f0 = *(const float4*)(xbase + (size_t)cn * HH);
            f1 = *(const float4*)(xbase + (size_t)cn * HH + HH);
        }
        // --- MFMA on current buffers ---
        bf16x8 af[2];
        #pragma unroll
        for (int mi = 0; mi < 2; mi++) {
            int m = wrow + mi * 16 + lcol;
            af[mi] = *(const bf16x8*)(sAu[cur] + m * 16 + ((quad ^ (m >> 3 & 3)) << 2));
        }
        #pragma unroll
        for (int ni = 0; ni < 2; ni++) {
            int n = wcol + ni * 16 + lcol;
            bf16x8 bfr = *(const bf16x8*)(sBu[cur] + n * 16 + ((quad ^ (n >> 3 & 3)) << 2));
            #pragma unroll
            for (int mi = 0; mi < 2; mi++)
                acc[mi][ni] = __builtin_amdgcn_mfma_f32_16x16x32_bf16(
                    af[mi], bfr, acc[mi][ni], 0, 0, 0);
        }
        // --- transpose + LDS-write next chunk (stalls on loads after MFMA) ---
        if (pf) {
            #pragma unroll
            for (int j = 0; j < 4; j++) {
                int q = tq * 4 + j;
                unsigned pk = (unsigned)r0.s[j] | ((unsigned)r1.s[j] << 16);
                sAu[alt][q * 16 + (((tp >> 2) ^ (q >> 3 & 3)) << 2) + (tp & 3)] = pk;
            }
            float a0[4] = {f0.x, f0.y, f0.z, f0.w};
            float a1[4] = {f1.x, f1.y, f1.z, f1.w};
            #pragma unroll
            for (int j = 0; j < 4; j++) {
                int h = tq * 4 + j;
                unsigned pk = pk2(a0[j] * cm0, a1[j] * cm1);
                sBu[alt][h * 16 + (((tp >> 2) ^ (h >> 3 & 3)) << 2) + (tp & 3)] = pk;
            }
        }
        __syncthreads();
    }
    // epilogue: scale by qm/colsum, write tmpT[h][q] packed b64
    #pragma unroll
    for (int mi = 0; mi < 2; mi++) {
        int qb = wrow + mi * 16 + quad * 4;
        #pragma unroll
        for (int ni = 0; ni < 2; ni++) {
            int h = wcol + ni * 16 + lcol;
            uint2 o;
            o.x = pk2(acc[mi][ni][0] * sInv[qb + 0], acc[mi][ni][1] * sInv[qb + 1]);
            o.y = pk2(acc[mi][ni][2] * sInv[qb + 2], acc[mi][ni][3] * sInv[qb + 3]);
            *(uint2*)(tmpT + ((size_t)b * HH + h0 + h) * QQ + q0 + qb) = o;
        }
    }
}

// ---------------- K3: c2q = (E/rowsum)·xqm ; q2c = (E/rowsum)·tmpT^T -------
// output-split (one acc per block), 2-phase double-buffered GLD16 staging
__global__ __launch_bounds__(256) void k_out(
    const unsigned short* __restrict__ Ebf, const unsigned short* __restrict__ xqmT,
    const unsigned short* __restrict__ tmpT, const float* __restrict__ rowsum,
    float* __restrict__ c2q, float* __restrict__ q2c) {
    int b  = blockIdx.z;
    int c0 = blockIdx.y * 128;
    int which = blockIdx.x & 1;
    int h0 = (blockIdx.x >> 1) * 128;
    const unsigned short* Bsrc = which ? tmpT : xqmT;
    float* dst = which ? q2c : c2q;
    int tid  = threadIdx.x;
    int lane = tid & 63, wave = tid >> 6;
    int quad = lane >> 4, lcol = lane & 15;
    int wrow = (wave >> 1) * 64, wcol = (wave & 1) * 64;

    __shared__ __align__(16) unsigned short sA[2][128][32];   // E    [c][q-chunk]
    __shared__ __align__(16) unsigned short sB[2][128][32];   // Bsrc [h][q-chunk]
    __shared__ float sInvR[128];
    if (tid < 128) sInvR[tid] = 1.0f / rowsum[(size_t)b * CC + c0 + tid];

    f32x4 acc[4][4];
    #pragma unroll
    for (int i = 0; i < 4; i++)
        #pragma unroll
        for (int j = 0; j < 4; j++) acc[i][j] = (f32x4)0.f;

    // ---- prologue: stage k-chunk 0 into buf 0 ----
    #pragma unroll
    for (int j = 0; j < 2; j++) {
        int chunk = wave * 2 + j;
        int row = chunk * 16 + (lane >> 2);
        int kb  = (lane & 3) * 8;
        GLD16(Ebf  + ((size_t)b * CC + c0 + row) * QQ + kb,
              (unsigned short*)sA[0] + chunk * 512);
        GLD16(Bsrc + ((size_t)b * HH + h0 + row) * QQ + kb,
              (unsigned short*)sB[0] + chunk * 512);
    }
    __syncthreads();

    for (int t = 0; t < 4; ++t) {
        int cur = t & 1, alt = cur ^ 1;
        bool pf = (t < 3);
        int kn = (t + 1) * 32;
        if (pf) {
            #pragma unroll
            for (int j = 0; j < 2; j++) {
                int chunk = wave * 2 + j;
                int row = chunk * 16 + (lane >> 2);
                int kb  = (lane & 3) * 8;
                GLD16(Ebf  + ((size_t)b * CC + c0 + row) * QQ + kn + kb,
                      (unsigned short*)sA[alt] + chunk * 512);
                GLD16(Bsrc + ((size_t)b * HH + h0 + row) * QQ + kn + kb,
                      (unsigned short*)sB[alt] + chunk * 512);
            }
        }
        bf16x8 af[4];
        #pragma unroll
        for (int mi = 0; mi < 4; mi++)
            af[mi] = *(const bf16x8*)&sA[cur][wrow + mi * 16 + lcol][quad * 8];
        #pragma unroll
        for (int ni = 0; ni < 4; ni++) {
            bf16x8 bfr = *(const bf16x8*)&sB[cur][wcol + ni * 16 + lcol][quad * 8];
            #pragma unroll
            for (int mi = 0; mi < 4; mi++)
                acc[mi][ni] = __builtin_amdgcn_mfma_f32_16x16x32_bf16(
                    af[mi], bfr, acc[mi][ni], 0, 0, 0);
        }
        __syncthreads();
    }
    #pragma unroll
    for (int mi = 0; mi < 4; mi++) {
        int rb = wrow + mi * 16 + quad * 4;
        float ir0 = sInvR[rb], ir1 = sInvR[rb + 1], ir2 = sInvR[rb + 2], ir3 = sInvR[rb + 3];
        #pragma unroll
        for (int ni = 0; ni < 4; ni++) {
            int col = h0 + wcol + ni * 16 + lcol;
            size_t o0 = ((size_t)b * CC + c0 + rb) * HH + col;
            dst[o0]          = acc[mi][ni][0] * ir0;
            dst[o0 + HH]     = acc[mi][ni][1] * ir1;
            dst[o0 + 2*HH]   = acc[mi][ni][2] * ir2;
            dst[o0 + 3*HH]   = acc[mi][ni][3] * ir3;
        }
    }
}

extern "C" void kernel_launch(void* const* d_in, const int* in_sizes, int n_in,
                              void* d_out, int out_size, void* d_ws, size_t ws_size,
                              hipStream_t stream) {
    const float* xc    = (const float*)d_in[0];
    const float* xq    = (const float*)d_in[1];
    const float* cmask = (const float*)d_in[2];
    const float* qmask = (const float*)d_in[3];
    const float* w0    = (const float*)d_in[4];
    const float* w1    = (const float*)d_in[5];
    const float* w2    = (const float*)d_in[6];
    const float* bias  = (const float*)d_in[7];

    float* out = (float*)d_out;
    float* c2q = out;
    float* q2c = out + (size_t)BB * CC * HH;

    unsigned short* Ebf   = (unsigned short*)d_ws;            // BB*CC*QQ
    unsigned short* xqw2b = Ebf   + (size_t)BB * CC * QQ;     // BB*QQ*HH
    unsigned short* xqmT  = xqw2b + (size_t)BB * QQ * HH;     // BB*HH*QQ
    unsigned short* tmpT  = xqmT  + (size_t)BB * QQ * HH;     // BB*HH*QQ
    float* rowsum = (float*)(tmpT + (size_t)BB * QQ * HH);    // BB*CC
    float* colsum = rowsum + (size_t)BB * CC;                 // BB*QQ
    float* sub0   = colsum + (size_t)BB * QQ;                 // BB*QQ

    k_sub0  <<<dim3(BB * QQ / 4),          256, 0, stream>>>(xq, w0, sub0, colsum);
    k_prep  <<<dim3(HH / 128, BB),         256, 0, stream>>>(xq, w2, qmask, xqw2b, xqmT);
    k_scores<<<dim3(CC / 64, BB),          256, 0, stream>>>(xc, xqw2b, w1, cmask, qmask,
                                                             bias, sub0, Ebf, rowsum, colsum);
    k_tmp   <<<dim3((HH / 64) * 2, BB),    256, 0, stream>>>(Ebf, xc, cmask, qmask,
                                                             colsum, tmpT);
    k_out   <<<dim3((HH / 128) * 2, CC / 128, BB), 256, 0, stream>>>(Ebf, xqmT, tmpT,
                                                                     rowsum, c2q, q2c);
}

// Round 3
// 458.094 us; speedup vs baseline: 1.0718x; 1.0718x over previous
//
#include <hip/hip_runtime.h>

#define BB 64
#define CC 1024
#define QQ 128
#define HH 512

typedef short bf16x8 __attribute__((ext_vector_type(8)));
typedef float f32x4 __attribute__((ext_vector_type(4)));

#define GLD16(g, l)                                                            \
    __builtin_amdgcn_global_load_lds(                                          \
        (const __attribute__((address_space(1))) unsigned int*)(g),            \
        (__attribute__((address_space(3))) unsigned int*)(l), 16, 0, 0)

__device__ __forceinline__ unsigned short f2bf(float f) {
    unsigned u = __float_as_uint(f);
    u += 0x7FFF + ((u >> 16) & 1);          // RNE
    return (unsigned short)(u >> 16);
}
__device__ __forceinline__ unsigned pk2(float lo, float hi) {
    return (unsigned)f2bf(lo) | ((unsigned)f2bf(hi) << 16);
}

// bijective XCD chunk swizzle (nwg % 8 == 0): XCD k owns contiguous [k*nwg/8, ...)
__device__ __forceinline__ unsigned xcd_swz(unsigned orig, unsigned nwg) {
    return (orig & 7u) * (nwg >> 3) + (orig >> 3);
}

// ---------------- K0: sub0[b,q] = dot(xq[b,q,:], W0); also zero colsum ----
__global__ __launch_bounds__(256) void k_sub0(const float* __restrict__ xq,
                                              const float* __restrict__ w0,
                                              float* __restrict__ sub0,
                                              float* __restrict__ colsum) {
    if (blockIdx.x < 32) colsum[blockIdx.x * 256 + threadIdx.x] = 0.0f;
    int wave = threadIdx.x >> 6;
    int lane = threadIdx.x & 63;
    int row  = blockIdx.x * 4 + wave;
    const float* p = xq + (size_t)row * HH + lane * 8;
    float4 a0 = *(const float4*)(p);
    float4 a1 = *(const float4*)(p + 4);
    float4 b0 = *(const float4*)(w0 + lane * 8);
    float4 b1 = *(const float4*)(w0 + lane * 8 + 4);
    float s = a0.x*b0.x + a0.y*b0.y + a0.z*b0.z + a0.w*b0.w
            + a1.x*b1.x + a1.y*b1.y + a1.z*b1.z + a1.w*b1.w;
    #pragma unroll
    for (int off = 32; off; off >>= 1) s += __shfl_xor(s, off);
    if (lane == 0) sub0[row] = s;
}

// ---------------- K_prep: xqw2b[q][h]=bf16(xq*w2); xqmT[h][q]=bf16(xq*qm) --
__global__ __launch_bounds__(256) void k_prep(const float* __restrict__ xq,
                                              const float* __restrict__ w2,
                                              const float* __restrict__ qmask,
                                              unsigned short* __restrict__ xqw2b,
                                              unsigned short* __restrict__ xqmT) {
    int b  = blockIdx.y;
    int ht = blockIdx.x * 128;
    int tid = threadIdx.x;
    __shared__ __align__(16) unsigned short sT[128][132];   // [q][h-local], pad

    {
        int q  = tid >> 1;
        int hh = (tid & 1) * 64;
        float qm = qmask[b * QQ + q];
        const float* xp = xq + ((size_t)b * QQ + q) * HH + ht + hh;
        unsigned short* wr = xqw2b + ((size_t)b * QQ + q) * HH + ht + hh;
        #pragma unroll
        for (int i = 0; i < 16; i++) {
            float4 v = *(const float4*)(xp + i * 4);
            float4 w = *(const float4*)(w2 + ht + hh + i * 4);
            uint2 pw; pw.x = pk2(v.x * w.x, v.y * w.y);
                      pw.y = pk2(v.z * w.z, v.w * w.w);
            *(uint2*)(wr + i * 4) = pw;
            uint2 pm; pm.x = pk2(v.x * qm, v.y * qm);
                      pm.y = pk2(v.z * qm, v.w * qm);
            *(uint2*)(&sT[q][hh + i * 4]) = pm;
        }
    }
    __syncthreads();
    {
        int h  = tid >> 1;
        int qh = (tid & 1) * 64;
        unsigned short* orow = xqmT + ((size_t)b * HH + ht + h) * QQ + qh;
        #pragma unroll
        for (int i = 0; i < 8; i++) {
            uint4 o;
            o.x = (unsigned)sT[qh + i*8 + 0][h] | ((unsigned)sT[qh + i*8 + 1][h] << 16);
            o.y = (unsigned)sT[qh + i*8 + 2][h] | ((unsigned)sT[qh + i*8 + 3][h] << 16);
            o.z = (unsigned)sT[qh + i*8 + 4][h] | ((unsigned)sT[qh + i*8 + 5][h] << 16);
            o.w = (unsigned)sT[qh + i*8 + 6][h] | ((unsigned)sT[qh + i*8 + 7][h] << 16);
            *(uint4*)(orow + i * 8) = o;
        }
    }
}

// ---------------- K1: S = xc · xqw2^T (MFMA) -> E=exp(S), rowsum, colsum ---
// c-tile 64, 2-phase db, XCD-swizzled (co-locate the 16 c-blocks per b)
__global__ __launch_bounds__(256) void k_scores(
    const float* __restrict__ xc, const unsigned short* __restrict__ xqw2b,
    const float* __restrict__ w1, const float* __restrict__ cmask,
    const float* __restrict__ qmask, const float* __restrict__ bias,
    const float* __restrict__ sub0, unsigned short* __restrict__ Ebf,
    float* __restrict__ rowsum, float* __restrict__ colsum) {
    unsigned swz = xcd_swz(blockIdx.x, CC / 64 * BB);   // 1024 blocks
    int b  = swz >> 4;
    int c0 = (swz & 15) * 64;
    int tid  = threadIdx.x;
    int lane = tid & 63, wave = tid >> 6;
    int quad = lane >> 4, lcol = lane & 15;
    int wrow = (wave >> 1) * 32, wcol = (wave & 1) * 64;

    __shared__ __align__(16) unsigned short sA[2][64][32];   // [c][k] bf16
    __shared__ __align__(16) unsigned short sB[2][128][32];  // [q][k] bf16
    __shared__ float sW1[512];
    __shared__ float sSub1[64];
    __shared__ float sS0[128], sQm[128], sCm[64];
    __shared__ float sRowP[2][64], sColP[2][128];

    sW1[tid] = w1[tid]; sW1[tid + 256] = w1[tid + 256];
    if (tid < 128) {
        sS0[tid] = sub0[b * QQ + tid] + bias[0];
        sQm[tid] = qmask[b * QQ + tid];
    }
    if (tid < 64) sCm[tid] = cmask[b * CC + c0 + tid];

    f32x4 acc[2][4];
    #pragma unroll
    for (int i = 0; i < 2; i++)
        #pragma unroll
        for (int j = 0; j < 4; j++) acc[i][j] = (f32x4)0.0f;
    float s1 = 0.0f;

    int arow = tid >> 2, akh = (tid & 3) * 8;
    const float* gbase = xc + ((size_t)(b * CC + c0 + arow)) * HH + akh;

    __syncthreads();   // sW1 ready

    // ---- prologue: stage chunk 0 into buf 0 ----
    {
        float4 v0 = *(const float4*)(gbase);
        float4 v1 = *(const float4*)(gbase + 4);
        const float* wp = sW1 + akh;
        s1 += v0.x*wp[0] + v0.y*wp[1] + v0.z*wp[2] + v0.w*wp[3]
            + v1.x*wp[4] + v1.y*wp[5] + v1.z*wp[6] + v1.w*wp[7];
        uint4 p;
        p.x = pk2(v0.x, v0.y); p.y = pk2(v0.z, v0.w);
        p.z = pk2(v1.x, v1.y); p.w = pk2(v1.z, v1.w);
        *(uint4*)&sA[0][arow][akh] = p;
    }
    #pragma unroll
    for (int j = 0; j < 2; j++) {
        int chunk = wave * 2 + j;
        int row = chunk * 16 + (lane >> 2);
        GLD16(xqw2b + ((size_t)b * QQ + row) * HH + (lane & 3) * 8,
              (unsigned short*)sB[0] + chunk * 512);
    }
    __syncthreads();

    for (int t = 0; t < 16; ++t) {
        int cur = t & 1, alt = cur ^ 1;
        bool pf = (t < 15);
        int kn = (t + 1) * 32;
        float4 v0, v1;
        if (pf) {
            const float* gp = gbase + kn;
            v0 = *(const float4*)(gp);
            v1 = *(const float4*)(gp + 4);
            #pragma unroll
            for (int j = 0; j < 2; j++) {
                int chunk = wave * 2 + j;
                int row = chunk * 16 + (lane >> 2);
                GLD16(xqw2b + ((size_t)b * QQ + row) * HH + kn + (lane & 3) * 8,
                      (unsigned short*)sB[alt] + chunk * 512);
            }
        }
        bf16x8 af[2];
        #pragma unroll
        for (int mi = 0; mi < 2; mi++)
            af[mi] = *(const bf16x8*)&sA[cur][wrow + mi * 16 + lcol][quad * 8];
        #pragma unroll
        for (int ni = 0; ni < 4; ni++) {
            bf16x8 bfr = *(const bf16x8*)&sB[cur][wcol + ni * 16 + lcol][quad * 8];
            #pragma unroll
            for (int mi = 0; mi < 2; mi++)
                acc[mi][ni] = __builtin_amdgcn_mfma_f32_16x16x32_bf16(
                    af[mi], bfr, acc[mi][ni], 0, 0, 0);
        }
        if (pf) {
            const float* wp = sW1 + kn + akh;
            s1 += v0.x*wp[0] + v0.y*wp[1] + v0.z*wp[2] + v0.w*wp[3]
                + v1.x*wp[4] + v1.y*wp[5] + v1.z*wp[6] + v1.w*wp[7];
            uint4 p;
            p.x = pk2(v0.x, v0.y); p.y = pk2(v0.z, v0.w);
            p.z = pk2(v1.x, v1.y); p.w = pk2(v1.z, v1.w);
            *(uint4*)&sA[alt][arow][akh] = p;
        }
        __syncthreads();
    }

    // sub1 finalize (4 k-groups per row)
    s1 += __shfl_xor(s1, 1);
    s1 += __shfl_xor(s1, 2);
    if ((tid & 3) == 0) sSub1[arow] = s1;
    __syncthreads();

    // epilogue: E = exp(S), rowsum/colsum partials
    float rsp[2][4];
    float csp[4] = {0.f, 0.f, 0.f, 0.f};
    #pragma unroll
    for (int mi = 0; mi < 2; mi++)
        #pragma unroll
        for (int r = 0; r < 4; r++) rsp[mi][r] = 0.f;

    #pragma unroll
    for (int mi = 0; mi < 2; mi++) {
        #pragma unroll
        for (int ni = 0; ni < 4; ni++) {
            int col = wcol + ni * 16 + lcol;
            float qm = sQm[col], s0 = sS0[col];
            #pragma unroll
            for (int r = 0; r < 4; r++) {
                int row = wrow + mi * 16 + quad * 4 + r;
                float e = __expf(acc[mi][ni][r] + sSub1[row] + s0);
                acc[mi][ni][r] = e;
                rsp[mi][r] += e * qm;
                csp[ni] += e * sCm[row];
            }
        }
    }
    #pragma unroll
    for (int mi = 0; mi < 2; mi++)
        #pragma unroll
        for (int r = 0; r < 4; r++) {
            float v = rsp[mi][r];
            v += __shfl_xor(v, 1); v += __shfl_xor(v, 2);
            v += __shfl_xor(v, 4); v += __shfl_xor(v, 8);
            if (lcol == 0) sRowP[wave & 1][wrow + mi * 16 + quad * 4 + r] = v;
        }
    #pragma unroll
    for (int ni = 0; ni < 4; ni++) {
        float v = csp[ni];
        v += __shfl_xor(v, 16); v += __shfl_xor(v, 32);
        if (quad == 0) sColP[wave >> 1][wcol + ni * 16 + lcol] = v;
    }
    // E store (bf16 scalar)
    #pragma unroll
    for (int mi = 0; mi < 2; mi++)
        #pragma unroll
        for (int ni = 0; ni < 4; ni++) {
            int col = wcol + ni * 16 + lcol;
            #pragma unroll
            for (int r = 0; r < 4; r++) {
                int row = wrow + mi * 16 + quad * 4 + r;
                Ebf[((size_t)(b * CC + c0 + row)) * QQ + col] = f2bf(acc[mi][ni][r]);
            }
        }
    __syncthreads();
    if (tid < 64)
        rowsum[(size_t)b * CC + c0 + tid] = sRowP[0][tid] + sRowP[1][tid];
    if (tid < 128)
        atomicAdd(&colsum[b * QQ + tid], sColP[0][tid] + sColP[1][tid]);
}

// ---------------- K2: tmpT[h][q] = qm[q]/colsum[q] * sum_c E[c][q]*mc*xc[c][h]
// full q=128 per block (single xc pass), 2-phase db, XCD-swizzled
__global__ __launch_bounds__(256) void k_tmp(
    const unsigned short* __restrict__ Ebf, const float* __restrict__ xc,
    const float* __restrict__ cmask, const float* __restrict__ qmask,
    const float* __restrict__ colsum, unsigned short* __restrict__ tmpT) {
    unsigned swz = xcd_swz(blockIdx.x, HH / 64 * BB);   // 512 blocks
    int b  = swz >> 3;
    int h0 = (swz & 7) * 64;
    int tid  = threadIdx.x;
    int lane = tid & 63, wave = tid >> 6;
    int quad = lane >> 4, lcol = lane & 15;
    int wrow = (wave >> 1) * 64;      // q
    int wcol = (wave & 1) * 32;       // h

    __shared__ __align__(16) unsigned int sAu[2][128 * 16];  // [q][c-chunk] swizzled
    __shared__ __align__(16) unsigned int sBu[2][64 * 16];   // [h][c-chunk] swizzled
    __shared__ float sInv[128];
    if (tid < 128) sInv[tid] = qmask[b * QQ + tid] / colsum[b * QQ + tid];

    f32x4 acc[4][2];
    #pragma unroll
    for (int i = 0; i < 4; i++) { acc[i][0] = (f32x4)0.f; acc[i][1] = (f32x4)0.f; }

    int tp = tid >> 4;     // c-pair 0..15
    int tq = tid & 15;     // q-8group / h-4group

    const unsigned short* ebase = Ebf + ((size_t)b * CC + 2 * tp) * QQ + tq * 8;
    const float*          xbase = xc  + ((size_t)b * CC + 2 * tp) * HH + h0 + tq * 4;
    const float*          mbase = cmask + (size_t)b * CC + 2 * tp;

    // ---- prologue: stage c-chunk 0 into buf 0 ----
    {
        union { uint4 v; unsigned short s[8]; } r0, r1;
        r0.v = *(const uint4*)(ebase);
        r1.v = *(const uint4*)(ebase + QQ);
        float cm0 = mbase[0];
        float cm1 = mbase[1];
        float4 f0 = *(const float4*)(xbase);
        float4 f1 = *(const float4*)(xbase + HH);
        #pragma unroll
        for (int j = 0; j < 8; j++) {
            int q = tq * 8 + j;
            unsigned pk = (unsigned)r0.s[j] | ((unsigned)r1.s[j] << 16);
            sAu[0][q * 16 + (((tp >> 2) ^ (q >> 3 & 3)) << 2) + (tp & 3)] = pk;
        }
        float a0[4] = {f0.x, f0.y, f0.z, f0.w};
        float a1[4] = {f1.x, f1.y, f1.z, f1.w};
        #pragma unroll
        for (int j = 0; j < 4; j++) {
            int h = tq * 4 + j;
            unsigned pk = pk2(a0[j] * cm0, a1[j] * cm1);
            sBu[0][h * 16 + (((tp >> 2) ^ (h >> 3 & 3)) << 2) + (tp & 3)] = pk;
        }
    }
    __syncthreads();

    for (int t = 0; t < 32; ++t) {
        int cur = t & 1, alt = cur ^ 1;
        bool pf = (t < 31);
        int cn = (t + 1) * 32;
        union { uint4 v; unsigned short s[8]; } r0, r1;
        float4 f0, f1;
        float cm0, cm1;
        if (pf) {
            r0.v = *(const uint4*)(ebase + (size_t)cn * QQ);
            r1.v = *(const uint4*)(ebase + (size_t)cn * QQ + QQ);
            cm0 = mbase[cn];
            cm1 = mbase[cn + 1];
            f0 = *(const float4*)(xbase + (size_t)cn * HH);
            f1 = *(const float4*)(xbase + (size_t)cn * HH + HH);
        }
        bf16x8 af[4];
        #pragma unroll
        for (int mi = 0; mi < 4; mi++) {
            int m = wrow + mi * 16 + lcol;
            af[mi] = *(const bf16x8*)(sAu[cur] + m * 16 + ((quad ^ (m >> 3 & 3)) << 2));
        }
        #pragma unroll
        for (int ni = 0; ni < 2; ni++) {
            int n = wcol + ni * 16 + lcol;
            bf16x8 bfr = *(const bf16x8*)(sBu[cur] + n * 16 + ((quad ^ (n >> 3 & 3)) << 2));
            #pragma unroll
            for (int mi = 0; mi < 4; mi++)
                acc[mi][ni] = __builtin_amdgcn_mfma_f32_16x16x32_bf16(
                    af[mi], bfr, acc[mi][ni], 0, 0, 0);
        }
        if (pf) {
            #pragma unroll
            for (int j = 0; j < 8; j++) {
                int q = tq * 8 + j;
                unsigned pk = (unsigned)r0.s[j] | ((unsigned)r1.s[j] << 16);
                sAu[alt][q * 16 + (((tp >> 2) ^ (q >> 3 & 3)) << 2) + (tp & 3)] = pk;
            }
            float a0[4] = {f0.x, f0.y, f0.z, f0.w};
            float a1[4] = {f1.x, f1.y, f1.z, f1.w};
            #pragma unroll
            for (int j = 0; j < 4; j++) {
                int h = tq * 4 + j;
                unsigned pk = pk2(a0[j] * cm0, a1[j] * cm1);
                sBu[alt][h * 16 + (((tp >> 2) ^ (h >> 3 & 3)) << 2) + (tp & 3)] = pk;
            }
        }
        __syncthreads();
    }
    // epilogue: scale by qm/colsum, write tmpT[h][q] packed b64
    #pragma unroll
    for (int mi = 0; mi < 4; mi++) {
        int qb = wrow + mi * 16 + quad * 4;
        #pragma unroll
        for (int ni = 0; ni < 2; ni++) {
            int h = wcol + ni * 16 + lcol;
            uint2 o;
            o.x = pk2(acc[mi][ni][0] * sInv[qb + 0], acc[mi][ni][1] * sInv[qb + 1]);
            o.y = pk2(acc[mi][ni][2] * sInv[qb + 2], acc[mi][ni][3] * sInv[qb + 3]);
            *(uint2*)(tmpT + ((size_t)b * HH + h0 + h) * QQ + qb) = o;
        }
    }
}

// ---------------- K3: c2q = (E/rowsum)·xqm ; q2c = (E/rowsum)·tmpT^T -------
// output-split, 2-phase db GLD16, XCD-swizzled (co-locate all 64 blocks per b)
__global__ __launch_bounds__(256) void k_out(
    const unsigned short* __restrict__ Ebf, const unsigned short* __restrict__ xqmT,
    const unsigned short* __restrict__ tmpT, const float* __restrict__ rowsum,
    float* __restrict__ c2q, float* __restrict__ q2c) {
    unsigned swz = xcd_swz(blockIdx.x, (HH / 128) * 2 * (CC / 128) * BB);  // 4096
    int x  = swz & 7;
    int c0 = ((swz >> 3) & 7) * 128;
    int b  = swz >> 6;
    int which = x & 1;
    int h0 = (x >> 1) * 128;
    const unsigned short* Bsrc = which ? tmpT : xqmT;
    float* dst = which ? q2c : c2q;
    int tid  = threadIdx.x;
    int lane = tid & 63, wave = tid >> 6;
    int quad = lane >> 4, lcol = lane & 15;
    int wrow = (wave >> 1) * 64, wcol = (wave & 1) * 64;

    __shared__ __align__(16) unsigned short sA[2][128][32];   // E    [c][q-chunk]
    __shared__ __align__(16) unsigned short sB[2][128][32];   // Bsrc [h][q-chunk]
    __shared__ float sInvR[128];
    if (tid < 128) sInvR[tid] = 1.0f / rowsum[(size_t)b * CC + c0 + tid];

    f32x4 acc[4][4];
    #pragma unroll
    for (int i = 0; i < 4; i++)
        #pragma unroll
        for (int j = 0; j < 4; j++) acc[i][j] = (f32x4)0.f;

    // ---- prologue: stage k-chunk 0 into buf 0 ----
    #pragma unroll
    for (int j = 0; j < 2; j++) {
        int chunk = wave * 2 + j;
        int row = chunk * 16 + (lane >> 2);
        int kb  = (lane & 3) * 8;
        GLD16(Ebf  + ((size_t)b * CC + c0 + row) * QQ + kb,
              (unsigned short*)sA[0] + chunk * 512);
        GLD16(Bsrc + ((size_t)b * HH + h0 + row) * QQ + kb,
              (unsigned short*)sB[0] + chunk * 512);
    }
    __syncthreads();

    for (int t = 0; t < 4; ++t) {
        int cur = t & 1, alt = cur ^ 1;
        bool pf = (t < 3);
        int kn = (t + 1) * 32;
        if (pf) {
            #pragma unroll
            for (int j = 0; j < 2; j++) {
                int chunk = wave * 2 + j;
                int row = chunk * 16 + (lane >> 2);
                int kb  = (lane & 3) * 8;
                GLD16(Ebf  + ((size_t)b * CC + c0 + row) * QQ + kn + kb,
                      (unsigned short*)sA[alt] + chunk * 512);
                GLD16(Bsrc + ((size_t)b * HH + h0 + row) * QQ + kn + kb,
                      (unsigned short*)sB[alt] + chunk * 512);
            }
        }
        bf16x8 af[4];
        #pragma unroll
        for (int mi = 0; mi < 4; mi++)
            af[mi] = *(const bf16x8*)&sA[cur][wrow + mi * 16 + lcol][quad * 8];
        #pragma unroll
        for (int ni = 0; ni < 4; ni++) {
            bf16x8 bfr = *(const bf16x8*)&sB[cur][wcol + ni * 16 + lcol][quad * 8];
            #pragma unroll
            for (int mi = 0; mi < 4; mi++)
                acc[mi][ni] = __builtin_amdgcn_mfma_f32_16x16x32_bf16(
                    af[mi], bfr, acc[mi][ni], 0, 0, 0);
        }
        __syncthreads();
    }
    #pragma unroll
    for (int mi = 0; mi < 4; mi++) {
        int rb = wrow + mi * 16 + quad * 4;
        float ir0 = sInvR[rb], ir1 = sInvR[rb + 1], ir2 = sInvR[rb + 2], ir3 = sInvR[rb + 3];
        #pragma unroll
        for (int ni = 0; ni < 4; ni++) {
            int col = h0 + wcol + ni * 16 + lcol;
            size_t o0 = ((size_t)b * CC + c0 + rb) * HH + col;
            dst[o0]          = acc[mi][ni][0] * ir0;
            dst[o0 + HH]     = acc[mi][ni][1] * ir1;
            dst[o0 + 2*HH]   = acc[mi][ni][2] * ir2;
            dst[o0 + 3*HH]   = acc[mi][ni][3] * ir3;
        }
    }
}

extern "C" void kernel_launch(void* const* d_in, const int* in_sizes, int n_in,
                              void* d_out, int out_size, void* d_ws, size_t ws_size,
                              hipStream_t stream) {
    const float* xc    = (const float*)d_in[0];
    const float* xq    = (const float*)d_in[1];
    const float* cmask = (const float*)d_in[2];
    const float* qmask = (const float*)d_in[3];
    const float* w0    = (const float*)d_in[4];
    const float* w1    = (const float*)d_in[5];
    const float* w2    = (const float*)d_in[6];
    const float* bias  = (const float*)d_in[7];

    float* out = (float*)d_out;
    float* c2q = out;
    float* q2c = out + (size_t)BB * CC * HH;

    unsigned short* Ebf   = (unsigned short*)d_ws;            // BB*CC*QQ
    unsigned short* xqw2b = Ebf   + (size_t)BB * CC * QQ;     // BB*QQ*HH
    unsigned short* xqmT  = xqw2b + (size_t)BB * QQ * HH;     // BB*HH*QQ
    unsigned short* tmpT  = xqmT  + (size_t)BB * QQ * HH;     // BB*HH*QQ
    float* rowsum = (float*)(tmpT + (size_t)BB * QQ * HH);    // BB*CC
    float* colsum = rowsum + (size_t)BB * CC;                 // BB*QQ
    float* sub0   = colsum + (size_t)BB * QQ;                 // BB*QQ

    k_sub0  <<<dim3(BB * QQ / 4),                 256, 0, stream>>>(xq, w0, sub0, colsum);
    k_prep  <<<dim3(HH / 128, BB),                256, 0, stream>>>(xq, w2, qmask, xqw2b, xqmT);
    k_scores<<<dim3(CC / 64 * BB),                256, 0, stream>>>(xc, xqw2b, w1, cmask, qmask,
                                                                    bias, sub0, Ebf, rowsum, colsum);
    k_tmp   <<<dim3(HH / 64 * BB),                256, 0, stream>>>(Ebf, xc, cmask, qmask,
                                                                    colsum, tmpT);
    k_out   <<<dim3((HH / 128) * 2 * (CC / 128) * BB), 256, 0, stream>>>(Ebf, xqmT, tmpT,
                                                                          rowsum, c2q, q2c);
}